// Round 1
// baseline (407.886 us; speedup 1.0000x reference)
//
#include <hip/hip_runtime.h>

typedef unsigned short u16;
typedef __attribute__((ext_vector_type(8))) short bf16x8;
typedef __attribute__((ext_vector_type(4))) float f32x4;

// ---- constants: B=8 N=4096 C=768 H=8 D=96, M = B*N = 32768 ----
#define M_TOT 32768

__device__ __forceinline__ u16 f2b(float x) {
    union { float f; unsigned u; } c; c.f = x;
    unsigned r = c.u + 0x7fffu + ((c.u >> 16) & 1u);  // RNE
    return (u16)(r >> 16);
}

// ============================================================
// prep_b1: B1[d,k] (96 x 1536 bf16), k<768 -> w1 * sum_h W_qkv_rgb[1536+h*96+d, k]
//                                    k>=768 -> w0 * sum_h W_qkv_depth[768+h*96+d, k-768]
// fb[d] = w1 * sum_h b_qkv_rgb[1536+h*96+d] + w0 * sum_h b_qkv_depth[768+h*96+d]
// (w0 = sigmoid(aw[0]) multiplies the depth-v branch, w1 = sigmoid(aw[1]) the rgb-v branch)
// ============================================================
__global__ void prep_b1(const float* __restrict__ Wr, const float* __restrict__ Wd,
                        const float* __restrict__ br, const float* __restrict__ bd,
                        const float* __restrict__ aw,
                        u16* __restrict__ B1, float* __restrict__ fb) {
    int id = blockIdx.x * 256 + threadIdx.x;
    if (id >= 96 * 1536) return;
    int d = id / 1536, k = id - d * 1536;
    float w0 = 1.f / (1.f + __expf(-aw[0]));
    float w1 = 1.f / (1.f + __expf(-aw[1]));
    float s = 0.f, v;
    if (k < 768) {
        for (int h = 0; h < 8; h++) s += Wr[(size_t)(1536 + h * 96 + d) * 768 + k];
        v = w1 * s;
    } else {
        for (int h = 0; h < 8; h++) s += Wd[(size_t)(768 + h * 96 + d) * 768 + (k - 768)];
        v = w0 * s;
    }
    B1[id] = f2b(v);
    if (k == 0) {
        float t = 0.f;
        for (int h = 0; h < 8; h++)
            t += w1 * br[1536 + h * 96 + d] + w0 * bd[768 + h * 96 + d];
        fb[d] = t;
    }
}

// ============================================================
// prep_weff: Weff[c,d] (768 x 96 bf16) = sum_h W_out[c, h*96+d]
// ============================================================
__global__ void prep_weff(const float* __restrict__ Wo, u16* __restrict__ Weff) {
    int id = blockIdx.x * 256 + threadIdx.x;
    if (id >= 768 * 96) return;
    int c = id / 96, d = id - c * 96;
    float s = 0.f;
    for (int h = 0; h < 8; h++) s += Wo[(size_t)c * 768 + h * 96 + d];
    Weff[id] = f2b(s);
}

// ============================================================
// gemm_f: f(32768 x 96) = [Xr | Xd](32768 x 1536) @ B1^T + fb, stored bf16.
// Also fuses the out0 = x_rgb passthrough copy into the A-staging (steps 0..11
// read every Xr element exactly once).
// Tile: M=64 per block (4 waves, 16 rows/wave), N=96 (all), BK=64, 24 K-steps.
// LDS padded to stride 72 elems (36 words -> 2 lanes/bank, conflict-free).
// ============================================================
#define LDF 72
__global__ __launch_bounds__(256) void gemm_f(const float* __restrict__ Xr,
                                              const float* __restrict__ Xd,
                                              const u16* __restrict__ B1,
                                              const float* __restrict__ fb,
                                              float* __restrict__ out0,
                                              u16* __restrict__ fbuf) {
    __shared__ u16 sA[64 * LDF];
    __shared__ u16 sB[96 * LDF];
    const int tid = threadIdx.x;
    const int m0 = blockIdx.x * 64;
    const int lane = tid & 63, wave = tid >> 6;
    const int fr = lane & 15, fk = (lane >> 4) * 8;

    f32x4 acc[6] = {};

    for (int ks = 0; ks < 24; ks++) {
        const int k0 = ks * 64;
        const float* __restrict__ X = (ks < 12) ? Xr : Xd;
        const int kx = (ks < 12) ? k0 : (k0 - 768);

        // ---- A stage: 64 rows x 64 cols fp32 -> bf16 (+ fused out0 copy) ----
#pragma unroll
        for (int r = 0; r < 4; r++) {
            int c = tid + 256 * r;            // 0..1023 : row = c/16, 16 float4 per row
            int row = c >> 4, colc = (c & 15) * 4;
            float4 v = *(const float4*)&X[(size_t)(m0 + row) * 768 + kx + colc];
            if (ks < 12)
                *(float4*)&out0[(size_t)(m0 + row) * 768 + k0 + colc] = v;
            ushort4 bv;
            bv.x = f2b(v.x); bv.y = f2b(v.y); bv.z = f2b(v.z); bv.w = f2b(v.w);
            *(ushort4*)&sA[row * LDF + colc] = bv;
        }
        // ---- B stage: 96 rows x 64 cols bf16 ----
#pragma unroll
        for (int r = 0; r < 3; r++) {
            int c = tid + 256 * r;            // 0..767 : row = c/8, 8 uint4 per row
            int row = c >> 3, colc = (c & 7) * 8;
            *(uint4*)&sB[row * LDF + colc] =
                *(const uint4*)&B1[(size_t)row * 1536 + k0 + colc];
        }
        __syncthreads();

        // ---- MFMA: wave handles rows wave*16..+16, 6 n-tiles, 2 sub-k ----
#pragma unroll
        for (int s = 0; s < 2; s++) {
            bf16x8 a = *(bf16x8*)&sA[(wave * 16 + fr) * LDF + s * 32 + fk];
#pragma unroll
            for (int j = 0; j < 6; j++) {
                bf16x8 b = *(bf16x8*)&sB[(j * 16 + fr) * LDF + s * 32 + fk];
                acc[j] = __builtin_amdgcn_mfma_f32_16x16x32_bf16(a, b, acc[j], 0, 0, 0);
            }
        }
        __syncthreads();
    }

    // ---- epilogue: +bias, store bf16. C/D: row=(lane>>4)*4+r, col=lane&15 ----
    const int em = (lane >> 4) * 4, en = lane & 15;
#pragma unroll
    for (int j = 0; j < 6; j++) {
        int dcol = j * 16 + en;
        float bias = fb[dcol];
#pragma unroll
        for (int r = 0; r < 4; r++) {
            int row = m0 + wave * 16 + em + r;
            fbuf[(size_t)row * 96 + dcol] = f2b(acc[j][r] + bias);
        }
    }
}

// ============================================================
// gemm_o: out1(32768 x 768) = fbuf(32768 x 96 bf16) @ Weff^T(768 x 96 bf16) + b_out (fp32 out)
// Tile 128x128, K=96 (3 sub-k, no K-loop). LDS stride 104 (52 words -> conflict-free).
// ============================================================
#define LDO 104
__global__ __launch_bounds__(256) void gemm_o(const u16* __restrict__ fbuf,
                                              const u16* __restrict__ Weff,
                                              const float* __restrict__ bout,
                                              float* __restrict__ out1) {
    __shared__ u16 sA[128 * LDO];
    __shared__ u16 sB[128 * LDO];
    const int tid = threadIdx.x;
    const int n0 = blockIdx.x * 128, m0 = blockIdx.y * 128;

    // stage: 128 rows x 96 cols each = 1536 uint4 chunks each, 6 per thread
#pragma unroll
    for (int r = 0; r < 6; r++) {
        int c = tid + 256 * r;                 // 0..1535 : 12 chunks per row
        int row = c / 12, colc = (c - row * 12) * 8;
        *(uint4*)&sA[row * LDO + colc] =
            *(const uint4*)&fbuf[(size_t)(m0 + row) * 96 + colc];
        *(uint4*)&sB[row * LDO + colc] =
            *(const uint4*)&Weff[(size_t)(n0 + row) * 96 + colc];
    }
    __syncthreads();

    const int lane = tid & 63, wave = tid >> 6;
    const int wm = (wave >> 1) * 64, wn = (wave & 1) * 64;
    const int fr = lane & 15, fk = (lane >> 4) * 8;

    f32x4 acc[4][4] = {};
#pragma unroll
    for (int s = 0; s < 3; s++) {
        bf16x8 a[4], b[4];
#pragma unroll
        for (int i = 0; i < 4; i++)
            a[i] = *(bf16x8*)&sA[(wm + i * 16 + fr) * LDO + s * 32 + fk];
#pragma unroll
        for (int j = 0; j < 4; j++)
            b[j] = *(bf16x8*)&sB[(wn + j * 16 + fr) * LDO + s * 32 + fk];
#pragma unroll
        for (int i = 0; i < 4; i++)
#pragma unroll
            for (int j = 0; j < 4; j++)
                acc[i][j] = __builtin_amdgcn_mfma_f32_16x16x32_bf16(a[i], b[j], acc[i][j], 0, 0, 0);
    }

    const int em = (lane >> 4) * 4, en = lane & 15;
#pragma unroll
    for (int j = 0; j < 4; j++) {
        int col = n0 + wn + j * 16 + en;
        float bias = bout[col];
#pragma unroll
        for (int i = 0; i < 4; i++) {
#pragma unroll
            for (int r = 0; r < 4; r++) {
                out1[(size_t)(m0 + wm + i * 16 + em + r) * 768 + col] = acc[i][j][r] + bias;
            }
        }
    }
}

// ============================================================
extern "C" void kernel_launch(void* const* d_in, const int* in_sizes, int n_in,
                              void* d_out, int out_size, void* d_ws, size_t ws_size,
                              hipStream_t stream) {
    const float* x_rgb       = (const float*)d_in[0];
    const float* x_depth     = (const float*)d_in[1];
    const float* W_qkv_rgb   = (const float*)d_in[2];
    const float* b_qkv_rgb   = (const float*)d_in[3];
    const float* W_qkv_depth = (const float*)d_in[4];
    const float* b_qkv_depth = (const float*)d_in[5];
    const float* W_out       = (const float*)d_in[6];
    const float* b_out       = (const float*)d_in[7];
    const float* aw          = (const float*)d_in[8];

    float* out0 = (float*)d_out;                      // x_rgb passthrough
    float* out1 = out0 + (size_t)M_TOT * 768;         // x_fusion

    // workspace layout (all 16B-aligned offsets); total ~6.8 MB
    char* w = (char*)d_ws;
    u16*   B1   = (u16*)w;                              // 96*1536*2   = 294912
    float* fb   = (float*)(w + 294912);                 // 96*4 (+pad) -> next at +512
    u16*   Weff = (u16*)(w + 294912 + 512);             // 768*96*2    = 147456
    u16*   fbuf = (u16*)(w + 294912 + 512 + 147456);    // 32768*96*2  = 6291456

    prep_b1<<<576, 256, 0, stream>>>(W_qkv_rgb, W_qkv_depth, b_qkv_rgb, b_qkv_depth,
                                     aw, B1, fb);
    prep_weff<<<288, 256, 0, stream>>>(W_out, Weff);
    gemm_f<<<512, 256, 0, stream>>>(x_rgb, x_depth, B1, fb, out0, fbuf);
    gemm_o<<<dim3(6, 256), 256, 0, stream>>>(fbuf, Weff, b_out, out1);
}